// Round 1
// baseline (461.368 us; speedup 1.0000x reference)
//
#include <hip/hip_runtime.h>

typedef short s16x8 __attribute__((ext_vector_type(8)));
typedef float f32x4 __attribute__((ext_vector_type(4)));

#define N_SAMPLES 65536
#define DIM 768
#define HID 384
#define NEXP 8
#define NCLS 8
#define JT 24   // HID/16
#define KT 24   // DIM/32

// workspace layout (bytes)
#define WS_CNT    0
#define WS_BUCKET 1024
#define WS_W1F    (WS_BUCKET + NEXP * N_SAMPLES * 4)   // 2,098,176

// RNE bf16 (prep only)
__device__ __forceinline__ unsigned short f2bf(float f) {
  union { float f; unsigned u; } v; v.f = f;
  unsigned r = v.u + 0x7fffu + ((v.u >> 16) & 1u);
  return (unsigned short)(r >> 16);
}

// fast half-up pair: 2x v_add + 1x v_perm = 1.5 VALU/element
// result: low16 = bf(a), high16 = bf(b)
__device__ __forceinline__ unsigned cvt2(float a, float b) {
  union { float f; unsigned u; } ua, ub;
  ua.f = a; ub.f = b;
  return __builtin_amdgcn_perm(ub.u + 0x8000u, ua.u + 0x8000u, 0x07060302u);
}

// lgkm-only barrier (CK block_sync_lds): does NOT drain vmcnt, so global
// register prefetches stay in flight across it.
#define LBAR asm volatile("s_waitcnt lgkmcnt(0)\n\ts_barrier" ::: "memory")

// W1[e][k=768][j=384] f32 -> W1F in MFMA A-fragment order:
// W1F[((e*JT+jt)*KT+kt)*64 + lane][i] = W1[e][kt*32+(lane>>4)*8+i][jt*16+(lane&15)]
__global__ void k_w1frag(const float* __restrict__ W1,
                         unsigned short* __restrict__ W1F,
                         int* __restrict__ cnt) {
  if (blockIdx.x == 0 && blockIdx.y == 0 && threadIdx.x < NEXP)
    cnt[threadIdx.x] = 0;
  const int e = blockIdx.x;
  const int unit = blockIdx.y * 4 + (threadIdx.x >> 6);   // (jt,kt) flat, 0..575
  const int lane = threadIdx.x & 63;
  const int jt = unit / KT, kt = unit % KT;
  const int j = jt * 16 + (lane & 15);
  const int k0 = kt * 32 + (lane >> 4) * 8;
  const float* src = W1 + ((size_t)e * DIM + k0) * HID + j;
  s16x8 v;
#pragma unroll
  for (int i = 0; i < 8; ++i) v[i] = (short)f2bf(src[(size_t)i * HID]);
  *(s16x8*)&W1F[(((size_t)e * JT * KT + unit) * 64 + lane) * 8] = v;
}

// bucket rows by expert
__global__ void k_scatter(const int* __restrict__ qt, int* __restrict__ cnt,
                          int* __restrict__ bucket) {
  __shared__ int lcnt[NEXP], lbase[NEXP];
  const int t = threadIdx.x;
  const int i = blockIdx.x * 256 + t;
  if (t < NEXP) lcnt[t] = 0;
  __syncthreads();
  const int e = qt[i];
  const int rank = atomicAdd(&lcnt[e], 1);
  __syncthreads();
  if (t < NEXP) lbase[t] = atomicAdd(&cnt[t], lcnt[t]);
  __syncthreads();
  bucket[(size_t)e * N_SAMPLES + lbase[e] + rank] = i;
}

// ---- k-loop building blocks (ring-indexed; loop is fully unrolled so all
// ring indices are compile-time constants -> registers, not scratch) ----

// load 8 floats of this thread's x row for k-step KS into ring slot
#define ALOADI(SLOT, KS)                                    \
  { const float4* p_ = (const float4*)(ap + (KS) * 32);     \
    aLo[SLOT] = p_[0]; aHi[SLOT] = p_[1]; }

// cvt 8 floats -> 16B ds_write_b128 into A tile ([64][40] bf16)
#define ASTOREI(BUF, SLOT)                                                  \
  { unsigned q0 = cvt2(aLo[SLOT].x, aLo[SLOT].y),                           \
             q1 = cvt2(aLo[SLOT].z, aLo[SLOT].w),                           \
             q2 = cvt2(aHi[SLOT].x, aHi[SLOT].y),                           \
             q3 = cvt2(aHi[SLOT].z, aHi[SLOT].w);                           \
    uint4 pk_ = {q0, q1, q2, q3};                                           \
    *(uint4*)&(BUF)[ar * 40 + aq * 8] = pk_; }

// 6 coalesced b128 fragment loads of W1F for k-step KS (from L2) into slot
#define WLOADI(SLOT, KS)                                                    \
  _Pragma("unroll") for (int ni = 0; ni < 6; ++ni)                          \
      wf[SLOT][ni] = *(const s16x8*)(wfbase + ((size_t)ni * KT + (KS)) * 512);

// 4 ds_read_b128 (x frags, 2-way free) + 24 MFMA; wf = A-operand (j), x = B (m)
#define COMPUTEI(AS, SLOT)                                                  \
  { _Pragma("unroll") for (int mi = 0; mi < 4; ++mi) {                      \
      s16x8 xfr = *(const s16x8*)&(AS)[(mi * 16 + lrow) * 40 + quad * 8];   \
      _Pragma("unroll") for (int ni = 0; ni < 6; ++ni)                      \
          acc[mi][ni] = __builtin_amdgcn_mfma_f32_16x16x32_bf16(            \
              wf[SLOT][ni], xfr, acc[mi][ni], 0, 0, 0); } }

// block = (expert e -> pinned XCD, 64 gathered rows, all 384 H)
// Pipeline: A-loads 4 k-steps deep (ring-4 regs), W-loads 2 deep (ring-3),
// one lgkm-only barrier per k-step. Issue order keeps every consumed load
// >=2 iterations old so compiler-inserted vmcnt waits are COUNTED (never 0):
// global prefetches stay in flight across barriers (T3/T4).
__global__ __launch_bounds__(256, 2) void k_moe_gemm(
    const float* __restrict__ x, const unsigned short* __restrict__ W1F,
    const float* __restrict__ b1, const float* __restrict__ W2,
    const float* __restrict__ b2, const int* __restrict__ cnt,
    const int* __restrict__ bucket, float* __restrict__ out) {
  // Hs (64x392 bf16 = 50 KB) overlays the two tiny A staging buffers.
  __shared__ __align__(16) short smem[25088];
  __shared__ __align__(16) short W2s[16 * 392];
  __shared__ float b1s[HID];
  __shared__ float b2s[NCLS];
  short* As0 = smem;            // [64 m][40 k-pad] bf16
  short* As1 = smem + 2560;
  short* Hs  = smem;            // [64 m][392 j] bf16

  const int e = blockIdx.x;
  const int n_e = cnt[e];
  if (n_e <= 0) return;         // uniform exit, no barrier crossed yet
  const int t = threadIdx.x;
  const int lane = t & 63;
  const int wave = t >> 6;
  const int lrow = lane & 15;
  const int quad = lane >> 4;
  const int ar = t >> 2;        // A staging row (0..63)
  const int aq = t & 3;         // A staging k-chunk (8 floats)

  for (int j = t; j < HID; j += 256) {
    b1s[j] = b1[e * HID + j];
    const float* wr = W2 + ((size_t)e * HID + j) * NCLS;
#pragma unroll
    for (int c = 0; c < NCLS; ++c) W2s[c * 392 + j] = (short)f2bf(wr[c]);
#pragma unroll
    for (int c = NCLS; c < 16; ++c) W2s[c * 392 + j] = 0;
  }
  if (t < NCLS) b2s[t] = b2[e * NCLS + t];

  // this wave's W1F base: jt = wave*6 + ni, per-kt stride 512 shorts
  const unsigned short* wfbase =
      W1F + ((size_t)(e * JT + wave * 6) * KT) * 512 + lane * 8;

  // first tile's gathered row index (later tiles prefetch under the k-loop)
  int aidx = 0;
  {
    const int rt0 = blockIdx.y;
    if (rt0 * 64 < n_e) {
      int slot = rt0 * 64 + ar;
      if (slot >= n_e) slot = n_e - 1;   // clamp: dup compute, masked store
      aidx = bucket[(size_t)e * N_SAMPLES + slot];
    }
  }

  for (int rt = blockIdx.y; rt * 64 < n_e; rt += gridDim.y) {
    const int row0 = rt * 64;
    const float* ap = x + (size_t)aidx * DIM + aq * 8;

    f32x4 acc[4][6];
#pragma unroll
    for (int mi = 0; mi < 4; ++mi)
#pragma unroll
      for (int ni = 0; ni < 6; ++ni) acc[mi][ni] = (f32x4){0.f, 0.f, 0.f, 0.f};

    float4 aLo[4], aHi[4];      // A ring: 4 k-steps in flight
    s16x8 wf[3][6];             // W ring: 2 k-steps ahead

    // prologue: fill the rings, stage k-step 0
    ALOADI(0, 0) ALOADI(1, 1) ALOADI(2, 2) ALOADI(3, 3)
    WLOADI(0, 0) WLOADI(1, 1)
    ASTOREI(As0, 0)             // counted wait: A1..A3,W0,W1 issued after A0

    // prefetch next tile's bucket index; latency hides under the k-loop
    int aidx_n = aidx;
    {
      const int nrt = rt + gridDim.y;
      if (nrt * 64 < n_e) {
        int s = nrt * 64 + ar;
        if (s >= n_e) s = n_e - 1;
        aidx_n = bucket[(size_t)e * N_SAMPLES + s];
      }
    }
    LBAR;   // As0 visible; all register prefetches stay in flight

#pragma unroll
    for (int ks = 0; ks < 24; ++ks) {
      short* bufc = (ks & 1) ? As1 : As0;   // compute buffer
      short* bufn = (ks & 1) ? As0 : As1;   // staging buffer
      // issue deep prefetches FIRST (oldest-needed loads stay oldest)
      if (ks + 4 < 24) ALOADI((ks + 4) & 3, ks + 4)
      if (ks + 2 < 24) WLOADI((ks + 2) % 3, ks + 2)
      // stage k-step ks+1: consumes A(ks+1), issued 3 iterations ago ->
      // compiler wait is vmcnt(~18), NOT 0; W/A prefetches keep flying
      if (ks + 1 < 24) ASTOREI(bufn, (ks + 1) & 3)
      // consume W(ks), issued 2 iterations ago (covers L2 latency)
      COMPUTEI(bufc, ks % 3)
      LBAR;   // bufn visible next step; bufc reads drained; vmcnt untouched
    }

    // epilogue 1: bias+relu -> Hs[m][j]; acc: col(lane&15)=m, row(quad*4+r)=j
    // 4 consecutive j per lane -> one ds_write_b64 each (no scalar u16 writes)
#pragma unroll
    for (int mi = 0; mi < 4; ++mi)
#pragma unroll
      for (int ni = 0; ni < 6; ++ni) {
        const int j = wave * 96 + ni * 16 + quad * 4;
        const float4 bb = *(const float4*)&b1s[j];
        float v0 = acc[mi][ni][0] + bb.x; v0 = v0 > 0.f ? v0 : 0.f;
        float v1 = acc[mi][ni][1] + bb.y; v1 = v1 > 0.f ? v1 : 0.f;
        float v2 = acc[mi][ni][2] + bb.z; v2 = v2 > 0.f ? v2 : 0.f;
        float v3 = acc[mi][ni][3] + bb.w; v3 = v3 > 0.f ? v3 : 0.f;
        uint2 pk = {cvt2(v0, v1), cvt2(v2, v3)};
        *(uint2*)&Hs[(mi * 16 + lrow) * 392 + j] = pk;
      }
    LBAR;

    // epilogue 2: layer-2 MFMA, M=64 (m-tile = wave), N=16 (8 valid), K=384
    {
      f32x4 acc2 = (f32x4){0.f, 0.f, 0.f, 0.f};
#pragma unroll
      for (int kk = 0; kk < 12; ++kk) {
        s16x8 af = *(const s16x8*)&Hs[(wave * 16 + lrow) * 392 + kk * 32 + quad * 8];
        s16x8 bf = *(const s16x8*)&W2s[lrow * 392 + kk * 32 + quad * 8];
        acc2 = __builtin_amdgcn_mfma_f32_16x16x32_bf16(af, bf, acc2, 0, 0, 0);
      }
      if (lrow < NCLS) {
        const float bb = b2s[lrow];
#pragma unroll
        for (int r = 0; r < 4; ++r) {
          const int m = wave * 16 + quad * 4 + r;
          if (row0 + m < n_e) {
            const int oi = bucket[(size_t)e * N_SAMPLES + row0 + m];
            out[(size_t)oi * NCLS + lrow] = acc2[r] + bb;
          }
        }
      }
    }
    LBAR;   // Hs reads done before next tile's A staging overwrites it
    aidx = aidx_n;
  }
}

extern "C" void kernel_launch(void* const* d_in, const int* in_sizes, int n_in,
                              void* d_out, int out_size, void* d_ws, size_t ws_size,
                              hipStream_t stream) {
  const float* x  = (const float*)d_in[0];
  const float* W1 = (const float*)d_in[1];
  const float* b1 = (const float*)d_in[2];
  const float* W2 = (const float*)d_in[3];
  const float* b2 = (const float*)d_in[4];
  const int* qt   = (const int*)d_in[5];
  float* out = (float*)d_out;
  char* ws = (char*)d_ws;

  int* cnt = (int*)(ws + WS_CNT);
  int* bucket = (int*)(ws + WS_BUCKET);
  unsigned short* W1F = (unsigned short*)(ws + WS_W1F);

  k_w1frag<<<dim3(8, 144), dim3(256), 0, stream>>>(W1, W1F, cnt);
  k_scatter<<<dim3(256), dim3(256), 0, stream>>>(qt, cnt, bucket);
  k_moe_gemm<<<dim3(8, 64), dim3(256), 0, stream>>>(x, W1F, b1, W2, b2, cnt, bucket, out);
}

// Round 2
// 346.053 us; speedup vs baseline: 1.3332x; 1.3332x over previous
//
#include <hip/hip_runtime.h>

typedef short s16x8 __attribute__((ext_vector_type(8)));
typedef float f32x4 __attribute__((ext_vector_type(4)));

#define N_SAMPLES 65536
#define DIM 768
#define HID 384
#define NEXP 8
#define NCLS 8
#define JT 24   // HID/16
#define KT 24   // DIM/32

// workspace layout (bytes)
#define WS_CNT    0
#define WS_BUCKET 1024
#define WS_W1F    (WS_BUCKET + NEXP * N_SAMPLES * 4)   // 2,098,176

// RNE bf16 (prep only)
__device__ __forceinline__ unsigned short f2bf(float f) {
  union { float f; unsigned u; } v; v.f = f;
  unsigned r = v.u + 0x7fffu + ((v.u >> 16) & 1u);
  return (unsigned short)(r >> 16);
}

// fast half-up pair: 2x v_add + 1x v_perm = 1.5 VALU/element
// result: low16 = bf(a), high16 = bf(b)
__device__ __forceinline__ unsigned cvt2(float a, float b) {
  union { float f; unsigned u; } ua, ub;
  ua.f = a; ub.f = b;
  return __builtin_amdgcn_perm(ub.u + 0x8000u, ua.u + 0x8000u, 0x07060302u);
}

// lgkm-only barrier (CK block_sync_lds): does NOT drain vmcnt, so global
// register prefetches stay in flight across it.
#define LBAR asm volatile("s_waitcnt lgkmcnt(0)\n\ts_barrier" ::: "memory")

// W1[e][k=768][j=384] f32 -> W1F in MFMA A-fragment order:
// W1F[((e*JT+jt)*KT+kt)*64 + lane][i] = W1[e][kt*32+(lane>>4)*8+i][jt*16+(lane&15)]
__global__ void k_w1frag(const float* __restrict__ W1,
                         unsigned short* __restrict__ W1F,
                         int* __restrict__ cnt) {
  if (blockIdx.x == 0 && blockIdx.y == 0 && threadIdx.x < NEXP)
    cnt[threadIdx.x] = 0;
  const int e = blockIdx.x;
  const int unit = blockIdx.y * 4 + (threadIdx.x >> 6);   // (jt,kt) flat, 0..575
  const int lane = threadIdx.x & 63;
  const int jt = unit / KT, kt = unit % KT;
  const int j = jt * 16 + (lane & 15);
  const int k0 = kt * 32 + (lane >> 4) * 8;
  const float* src = W1 + ((size_t)e * DIM + k0) * HID + j;
  s16x8 v;
#pragma unroll
  for (int i = 0; i < 8; ++i) v[i] = (short)f2bf(src[(size_t)i * HID]);
  *(s16x8*)&W1F[(((size_t)e * JT * KT + unit) * 64 + lane) * 8] = v;
}

// bucket rows by expert
__global__ void k_scatter(const int* __restrict__ qt, int* __restrict__ cnt,
                          int* __restrict__ bucket) {
  __shared__ int lcnt[NEXP], lbase[NEXP];
  const int t = threadIdx.x;
  const int i = blockIdx.x * 256 + t;
  if (t < NEXP) lcnt[t] = 0;
  __syncthreads();
  const int e = qt[i];
  const int rank = atomicAdd(&lcnt[e], 1);
  __syncthreads();
  if (t < NEXP) lbase[t] = atomicAdd(&cnt[t], lcnt[t]);
  __syncthreads();
  bucket[(size_t)e * N_SAMPLES + lbase[e] + rank] = i;
}

// ---- k-loop building blocks. ALL slot references are distinct C
// identifiers (aLo0..aLo3, wfA/wfB) -- no runtime ring indices, so nothing
// can be demoted to scratch (rule #20; round-1 regression was exactly that:
// WRITE_SIZE 2MB -> 126MB of spill traffic). ----

// load 8 floats of this thread's x row for k-step KS into named slot S
#define ALOADN(S, KS)                                       \
  { const float4* p_ = (const float4*)(ap + (KS) * 32);     \
    aLo##S = p_[0]; aHi##S = p_[1]; }

// cvt named slot -> 16B ds_write_b128 into A tile ([64][40] bf16)
#define ASTOREN(BUF, S)                                                     \
  { unsigned q0 = cvt2(aLo##S.x, aLo##S.y), q1 = cvt2(aLo##S.z, aLo##S.w),  \
             q2 = cvt2(aHi##S.x, aHi##S.y), q3 = cvt2(aHi##S.z, aHi##S.w);  \
    uint4 pk_ = {q0, q1, q2, q3};                                           \
    *(uint4*)&(BUF)[ar * 40 + aq * 8] = pk_; }

// 6 coalesced b128 fragment loads of W1F for k-step KS (from L2)
#define WLOADN(WF, KS)                                                      \
  _Pragma("unroll") for (int ni = 0; ni < 6; ++ni)                          \
      WF[ni] = *(const s16x8*)(wfbase + ((size_t)ni * KT + (KS)) * 512);

// 4 ds_read_b128 (x frags, 2-way free) + 24 MFMA; wf = A-operand (j), x = B (m)
#define COMPUTE(AS, WF)                                                     \
  { _Pragma("unroll") for (int mi = 0; mi < 4; ++mi) {                      \
      s16x8 xfr = *(const s16x8*)&(AS)[(mi * 16 + lrow) * 40 + quad * 8];   \
      _Pragma("unroll") for (int ni = 0; ni < 6; ++ni)                      \
          acc[mi][ni] = __builtin_amdgcn_mfma_f32_16x16x32_bf16(            \
              WF[ni], xfr, acc[mi][ni], 0, 0, 0); } }

// One pipelined k-step: stage next LDS buffer from a 3-step-old register
// slot (compiler wait = counted vmcnt, ~10-16 younger loads stay in
// flight), refill that slot 4 steps ahead, compute from a 2-step-old W
// slot, refill it 2 ahead. One lgkm-only barrier per step.
#define KSTEP(ASC, ASN, SN, SF, KA, WF, KW) \
  ASTOREN(ASN, SN)                          \
  ALOADN(SF, KA)                            \
  COMPUTE(ASC, WF)                          \
  WLOADN(WF, KW)                            \
  LBAR;

// block = (expert e -> pinned XCD, 64 gathered rows, all 384 H)
__global__ __launch_bounds__(256, 2) void k_moe_gemm(
    const float* __restrict__ x, const unsigned short* __restrict__ W1F,
    const float* __restrict__ b1, const float* __restrict__ W2,
    const float* __restrict__ b2, const int* __restrict__ cnt,
    const int* __restrict__ bucket, float* __restrict__ out) {
  // Hs (64x392 bf16 = 50 KB) overlays the two tiny A staging buffers.
  __shared__ __align__(16) short smem[25088];
  __shared__ __align__(16) short W2s[16 * 392];
  __shared__ float b1s[HID];
  __shared__ float b2s[NCLS];
  short* As0 = smem;            // [64 m][40 k-pad] bf16
  short* As1 = smem + 2560;
  short* Hs  = smem;            // [64 m][392 j] bf16

  const int e = blockIdx.x;
  const int n_e = cnt[e];
  if (n_e <= 0) return;         // uniform exit, no barrier crossed yet
  const int t = threadIdx.x;
  const int lane = t & 63;
  const int wave = t >> 6;
  const int lrow = lane & 15;
  const int quad = lane >> 4;
  const int ar = t >> 2;        // A staging row (0..63)
  const int aq = t & 3;         // A staging k-chunk (8 floats)

  for (int j = t; j < HID; j += 256) {
    b1s[j] = b1[e * HID + j];
    const float* wr = W2 + ((size_t)e * HID + j) * NCLS;
#pragma unroll
    for (int c = 0; c < NCLS; ++c) W2s[c * 392 + j] = (short)f2bf(wr[c]);
#pragma unroll
    for (int c = NCLS; c < 16; ++c) W2s[c * 392 + j] = 0;
  }
  if (t < NCLS) b2s[t] = b2[e * NCLS + t];

  // this wave's W1F base: jt = wave*6 + ni, per-kt stride 512 shorts
  const unsigned short* wfbase =
      W1F + ((size_t)(e * JT + wave * 6) * KT) * 512 + lane * 8;

  // first tile's gathered row index (later tiles prefetch under the k-loop)
  int aidx = 0;
  {
    const int rt0 = blockIdx.y;
    if (rt0 * 64 < n_e) {
      int slot = rt0 * 64 + ar;
      if (slot >= n_e) slot = n_e - 1;   // clamp: dup compute, masked store
      aidx = bucket[(size_t)e * N_SAMPLES + slot];
    }
  }

  for (int rt = blockIdx.y; rt * 64 < n_e; rt += gridDim.y) {
    const int row0 = rt * 64;
    const float* ap = x + (size_t)aidx * DIM + aq * 8;

    f32x4 acc[4][6];
#pragma unroll
    for (int mi = 0; mi < 4; ++mi)
#pragma unroll
      for (int ni = 0; ni < 6; ++ni) acc[mi][ni] = (f32x4){0.f, 0.f, 0.f, 0.f};

    float4 aLo0, aHi0, aLo1, aHi1, aLo2, aHi2, aLo3, aHi3;  // A ring, named
    s16x8 wfA[6], wfB[6];                                   // W ring, named

    // prologue: fill rings (A: steps 0-3, W: steps 0-1), stage step 0.
    // ASTORE of slot0 waits with 18 younger loads outstanding -> vmcnt(18).
    ALOADN(0, 0) ALOADN(1, 1) ALOADN(2, 2) ALOADN(3, 3)
    WLOADN(wfA, 0) WLOADN(wfB, 1)
    ASTOREN(As0, 0)

    // prefetch next tile's bucket index; latency hides under the k-loop
    int aidx_n = aidx;
    {
      const int nrt = rt + gridDim.y;
      if (nrt * 64 < n_e) {
        int s = nrt * 64 + ar;
        if (s >= n_e) s = n_e - 1;
        aidx_n = bucket[(size_t)e * N_SAMPLES + s];
      }
    }
    LBAR;   // As0 visible; all register prefetches stay in flight

    // steady state: 5 unguarded period-4 bodies cover k-steps 0..19.
    // Slot invariant at step ks (ks%4==0): s1=ks+1 s2=ks+2 s3=ks+3 s0=ks+4(being loaded)
    for (int kb = 0; kb < 20; kb += 4) {
      KSTEP(As0, As1, 1, 0, kb + 4, wfA, kb + 2)
      KSTEP(As1, As0, 2, 1, kb + 5, wfB, kb + 3)
      KSTEP(As0, As1, 3, 2, kb + 6, wfA, kb + 4)
      KSTEP(As1, As0, 0, 3, kb + 7, wfB, kb + 5)
    }

    // epilogue: steps 20..23, no further A loads
    ASTOREN(As1, 1) COMPUTE(As0, wfA) WLOADN(wfA, 22) LBAR;   // step 20
    ASTOREN(As0, 2) COMPUTE(As1, wfB) WLOADN(wfB, 23) LBAR;   // step 21
    ASTOREN(As1, 3) COMPUTE(As0, wfA) LBAR;                   // step 22
    COMPUTE(As1, wfB) LBAR;                                   // step 23

    // epilogue 1: bias+relu -> Hs[m][j]; acc: col(lane&15)=m, row(quad*4+r)=j
    // 4 consecutive j per lane -> one ds_write_b64 each (no scalar u16 writes)
#pragma unroll
    for (int mi = 0; mi < 4; ++mi)
#pragma unroll
      for (int ni = 0; ni < 6; ++ni) {
        const int j = wave * 96 + ni * 16 + quad * 4;
        const float4 bb = *(const float4*)&b1s[j];
        float v0 = acc[mi][ni][0] + bb.x; v0 = v0 > 0.f ? v0 : 0.f;
        float v1 = acc[mi][ni][1] + bb.y; v1 = v1 > 0.f ? v1 : 0.f;
        float v2 = acc[mi][ni][2] + bb.z; v2 = v2 > 0.f ? v2 : 0.f;
        float v3 = acc[mi][ni][3] + bb.w; v3 = v3 > 0.f ? v3 : 0.f;
        uint2 pk = {cvt2(v0, v1), cvt2(v2, v3)};
        *(uint2*)&Hs[(mi * 16 + lrow) * 392 + j] = pk;
      }
    LBAR;

    // epilogue 2: layer-2 MFMA, M=64 (m-tile = wave), N=16 (8 valid), K=384
    {
      f32x4 acc2 = (f32x4){0.f, 0.f, 0.f, 0.f};
#pragma unroll
      for (int kk = 0; kk < 12; ++kk) {
        s16x8 af = *(const s16x8*)&Hs[(wave * 16 + lrow) * 392 + kk * 32 + quad * 8];
        s16x8 bf = *(const s16x8*)&W2s[lrow * 392 + kk * 32 + quad * 8];
        acc2 = __builtin_amdgcn_mfma_f32_16x16x32_bf16(af, bf, acc2, 0, 0, 0);
      }
      if (lrow < NCLS) {
        const float bb = b2s[lrow];
#pragma unroll
        for (int r = 0; r < 4; ++r) {
          const int m = wave * 16 + quad * 4 + r;
          if (row0 + m < n_e) {
            const int oi = bucket[(size_t)e * N_SAMPLES + row0 + m];
            out[(size_t)oi * NCLS + lrow] = acc2[r] + bb;
          }
        }
      }
    }
    LBAR;   // Hs reads done before next tile's A staging overwrites it
    aidx = aidx_n;
  }
}

extern "C" void kernel_launch(void* const* d_in, const int* in_sizes, int n_in,
                              void* d_out, int out_size, void* d_ws, size_t ws_size,
                              hipStream_t stream) {
  const float* x  = (const float*)d_in[0];
  const float* W1 = (const float*)d_in[1];
  const float* b1 = (const float*)d_in[2];
  const float* W2 = (const float*)d_in[3];
  const float* b2 = (const float*)d_in[4];
  const int* qt   = (const int*)d_in[5];
  float* out = (float*)d_out;
  char* ws = (char*)d_ws;

  int* cnt = (int*)(ws + WS_CNT);
  int* bucket = (int*)(ws + WS_BUCKET);
  unsigned short* W1F = (unsigned short*)(ws + WS_W1F);

  k_w1frag<<<dim3(8, 144), dim3(256), 0, stream>>>(W1, W1F, cnt);
  k_scatter<<<dim3(256), dim3(256), 0, stream>>>(qt, cnt, bucket);
  k_moe_gemm<<<dim3(8, 64), dim3(256), 0, stream>>>(x, W1F, b1, W2, b2, cnt, bucket, out);
}